// Round 11
// baseline (533.089 us; speedup 1.0000x reference)
//
#include <hip/hip_runtime.h>

// GIN 3-layer forward on MI355X — round 11: per-layer fused gather+MLP kernel
// (gather -> LDS tile -> MFMA), 9 dispatches total.

constexpr int Nn = 50000;
constexpr int Ne = 600000;

typedef __attribute__((ext_vector_type(8))) short short8;
typedef __attribute__((ext_vector_type(4))) float f32x4;

// ---------------- bf16 helpers -------------------------------------------
__device__ inline float bflo(uint u) { return __uint_as_float(u << 16); }
__device__ inline float bfhi(uint u) { return __uint_as_float(u & 0xffff0000u); }
__device__ inline ushort f2b(float f) {
  uint x = __float_as_uint(f);
  return (ushort)((x + 0x7fffu + ((x >> 16) & 1u)) >> 16);  // RNE, finite vals
}
__device__ inline uint pack2(float a, float b) {
  return (uint)f2b(a) | ((uint)f2b(b) << 16);
}

// ---------------- fused prep: cvt_bf16 | pack_w | edge_hist ---------------
constexpr int CVT_B = (Nn * 32) / 256;        // 6250
constexpr int PK_B = (5 * 2048) / 256;        // 40
constexpr int EH_B = (Ne + 255) / 256;        // 2344
__global__ __launch_bounds__(256) void prep_all(
    const float4* __restrict__ x4, uint2* __restrict__ xb,
    const float* __restrict__ Wa, const float* __restrict__ Wb,
    const float* __restrict__ Wc, const float* __restrict__ Wd,
    const float* __restrict__ We, ushort* __restrict__ pw,
    const int* __restrict__ dst, int* __restrict__ rp) {
  int b = blockIdx.x;
  if (b < CVT_B) {
    int i = b * 256 + threadIdx.x;
    float4 v = x4[i];
    xb[i] = make_uint2(pack2(v.x, v.y), pack2(v.z, v.w));
  } else if (b < CVT_B + PK_B) {
    int t = (b - CVT_B) * 256 + threadIdx.x;
    int mat = t >> 11;
    int r = t & 2047;
    int lane = r & 63;
    int ktnt = r >> 6;
    int kt = ktnt & 3, nt = ktnt >> 2;
    const float* W = mat == 0 ? Wa : mat == 1 ? Wb : mat == 2 ? Wc : mat == 3 ? Wd : We;
    int c = nt * 16 + (lane & 15);
    int k0 = kt * 32 + 8 * (lane >> 4);
    ushort tmp[8];
#pragma unroll
    for (int j = 0; j < 8; j++) tmp[j] = f2b(W[(size_t)(k0 + j) * 128 + c]);
    *(uint4*)&pw[(size_t)mat * 16384 + r * 8] = *(uint4*)tmp;
  } else {
    int e = (b - CVT_B - PK_B) * 256 + threadIdx.x;
    if (e < Ne) atomicAdd(&rp[dst[e] + 1], 1);
  }
}

// ---------------- CSR scan ------------------------------------------------
constexpr int SCAN_N = Nn + 1;
constexpr int SCAN_G = (SCAN_N + 1023) / 1024;  // 49

__global__ __launch_bounds__(1024) void scan_p1(int* __restrict__ rp,
                                                int* __restrict__ bsum) {
  __shared__ int wsum[16];
  __shared__ int wpre[16];
  int i = blockIdx.x * 1024 + threadIdx.x;
  int lane = threadIdx.x & 63, wv = threadIdx.x >> 6;
  int v = (i < SCAN_N) ? rp[i] : 0;
#pragma unroll
  for (int off = 1; off < 64; off <<= 1) {
    int t = __shfl_up(v, off);
    if (lane >= off) v += t;
  }
  if (lane == 63) wsum[wv] = v;
  __syncthreads();
  if (threadIdx.x == 0) {
    int acc = 0;
#pragma unroll
    for (int w = 0; w < 16; w++) {
      wpre[w] = acc;
      acc += wsum[w];
    }
    bsum[blockIdx.x] = acc;
  }
  __syncthreads();
  if (i < SCAN_N) rp[i] = v + wpre[wv];
}

// phase 2+3 merged: each block wave-reduces its prefix of bsum, adds offsets
__global__ __launch_bounds__(1024) void scan_p3m(int* __restrict__ rp,
                                                 const int* __restrict__ bsum,
                                                 int* __restrict__ cur) {
  __shared__ int off_s;
  if (threadIdx.x < 64) {
    int v = (threadIdx.x < blockIdx.x) ? bsum[threadIdx.x] : 0;  // SCAN_G<=64
#pragma unroll
    for (int o = 1; o < 64; o <<= 1) v += __shfl_xor(v, o);
    if (threadIdx.x == 0) off_s = v;
  }
  __syncthreads();
  int off = off_s;
  int i = blockIdx.x * 1024 + threadIdx.x;
  if (i < SCAN_N) {
    int v = rp[i] + off;
    rp[i] = v;
    if (i < Nn) cur[i] = v;
  }
}

__global__ __launch_bounds__(256) void edge_fill(const int* __restrict__ src,
                                                 const int* __restrict__ dst,
                                                 int* __restrict__ cur,
                                                 int* __restrict__ cols) {
  int e = blockIdx.x * 256 + threadIdx.x;
  if (e < Ne) {
    int p = atomicAdd(&cur[dst[e]], 1);
    cols[p] = src[e];
  }
}

// ---------------- per-wave node gather into LDS row -----------------------
// node is wave-uniform; lane l accumulates uint l (feats 2l,2l+1) of the row.
template <bool FOLD>
__device__ inline void gather_node(const uint* __restrict__ X,
                                   const int* __restrict__ rp,
                                   const int* __restrict__ cols, int node, int l,
                                   float A0, float A1, float B0, float B1,
                                   uint* __restrict__ htrow) {
  int p0 = rp[node], p1 = rp[node + 1];
  int deg = p1 - p0;
  uint su = X[(size_t)node * 64 + l];
  float ax = bflo(su), ay = bfhi(su);
  if (deg > 0) {
    int ci = p0 + (l & 31);
    int cv = cols[ci < p1 ? ci : p1 - 1];
    if (deg <= 16) {
#pragma unroll
      for (int j = 0; j < 16; j++) {
        int s = __shfl(cv, j);
        uint u = X[(size_t)s * 64 + l];
        float m = j < deg ? 1.f : 0.f;
        ax = fmaf(m, bflo(u), ax);
        ay = fmaf(m, bfhi(u), ay);
      }
    } else {
#pragma unroll
      for (int j = 0; j < 32; j++) {
        int s = __shfl(cv, j);
        uint u = X[(size_t)s * 64 + l];
        float m = j < deg ? 1.f : 0.f;
        ax = fmaf(m, bflo(u), ax);
        ay = fmaf(m, bfhi(u), ay);
      }
      for (int p = p0 + 32; p < p1; ++p) {
        int s = cols[p];  // uniform address -> scalar load
        uint u = X[(size_t)s * 64 + l];
        ax += bflo(u);
        ay += bfhi(u);
      }
    }
  }
  float cnt = (float)(deg + 1);
  float ox = FOLD ? A0 * ax + cnt * B0 : ax;
  float oy = FOLD ? A1 * ay + cnt * B1 : ay;
  htrow[l] = pack2(ox, oy);
}

// ---------------- fused layer: gather + relu(relu(H@Wa+ba)@Wb+bb) + stats -
constexpr int MLP_ROWS = 128;  // 2 row-tiles of 64
template <bool FOLD>
__global__ __launch_bounds__(256, 2) void gin_fused(
    const uint* __restrict__ X, const int* __restrict__ rp,
    const int* __restrict__ cols, const float* __restrict__ sums,
    const float* __restrict__ gamma, const float* __restrict__ beta,
    const uint4* __restrict__ pWa, const float* __restrict__ ba,
    const short8* __restrict__ pWb, const float* __restrict__ bb,
    ushort* __restrict__ C, float* __restrict__ stats) {
  __shared__ uint4 W1l[2048];    // 32KB W1 fragments
  __shared__ ushort T[64][136];  // 17.4KB intermediate
  __shared__ uint Ht[64][68];    // 17.4KB gathered tile (272B row stride)
  __shared__ float sS[128], sQ[128];
  int tid = threadIdx.x;
#pragma unroll
  for (int i = 0; i < 8; i++) W1l[tid + i * 256] = pWa[tid + i * 256];
  if (tid < 128) {
    sS[tid] = 0.f;
    sQ[tid] = 0.f;
  }
  int wv = tid >> 6, l = tid & 63, lr = l & 15, lg = l >> 4;
  int rowb = wv * 16 + lr;
  int row0 = blockIdx.x * MLP_ROWS;

  float A0 = 1.f, A1 = 1.f, B0 = 0.f, B1 = 0.f;
  if (FOLD) {
    int f0 = l * 2;
    float m0 = sums[f0] * (1.f / Nn), m1 = sums[f0 + 1] * (1.f / Nn);
    float v0 = sums[128 + f0] * (1.f / Nn) - m0 * m0;
    float v1 = sums[128 + f0 + 1] * (1.f / Nn) - m1 * m1;
    A0 = rsqrtf(v0 + 1e-5f) * gamma[f0];
    A1 = rsqrtf(v1 + 1e-5f) * gamma[f0 + 1];
    B0 = beta[f0] - m0 * A0;
    B1 = beta[f0 + 1] - m1 * A1;
  }

  short8 w2r[8][4];
#pragma unroll
  for (int nt = 0; nt < 8; nt++)
#pragma unroll
    for (int kt = 0; kt < 4; kt++) w2r[nt][kt] = pWb[(nt * 4 + kt) * 64 + l];
  __builtin_amdgcn_sched_barrier(0);

  for (int rt = 0; rt < MLP_ROWS / 64; rt++) {
    int base = row0 + rt * 64;
    // ---- gather phase: wave wv fills Ht rows wv*16..wv*16+15 ----
    for (int i = 0; i < 16; i++) {
      int node = base + wv * 16 + i;
      if (node < Nn) {
        gather_node<FOLD>(X, rp, cols, node, l, A0, A1, B0, B1, &Ht[wv * 16 + i][0]);
      } else {
        Ht[wv * 16 + i][l] = 0;
      }
    }
    __syncthreads();  // Ht ready (also: prev tile's T fully consumed)

    // ---- GEMM1 from Ht (LDS) with W1 (LDS) ----
    short8 afr[4];
#pragma unroll
    for (int kt = 0; kt < 4; kt++)
      afr[kt] = *(const short8*)&Ht[rowb][kt * 16 + lg * 4];
    f32x4 acc[8];
#pragma unroll
    for (int nt = 0; nt < 8; nt++) {
      float4 bv = *(const float4*)&ba[nt * 16 + lg * 4];
      acc[nt][0] = bv.x; acc[nt][1] = bv.y; acc[nt][2] = bv.z; acc[nt][3] = bv.w;
    }
#pragma unroll
    for (int kt = 0; kt < 4; kt++)
#pragma unroll
      for (int nt = 0; nt < 8; nt++) {
        short8 w1 = *(const short8*)&W1l[(nt * 4 + kt) * 64 + l];
        acc[nt] = __builtin_amdgcn_mfma_f32_16x16x32_bf16(w1, afr[kt], acc[nt],
                                                          0, 0, 0);
      }
#pragma unroll
    for (int nt = 0; nt < 8; nt++) {
      float v0 = fmaxf(acc[nt][0], 0.f), v1 = fmaxf(acc[nt][1], 0.f);
      float v2 = fmaxf(acc[nt][2], 0.f), v3 = fmaxf(acc[nt][3], 0.f);
      *(uint2*)&T[rowb][nt * 16 + lg * 4] = make_uint2(pack2(v0, v1), pack2(v2, v3));
    }
    __syncthreads();  // T ready (Ht consumed above)

    // ---- GEMM2 with W2 (regs) ----
    int row = base + rowb;
    bool ok = row < Nn;
    short8 tfr[4];
#pragma unroll
    for (int kt = 0; kt < 4; kt++) tfr[kt] = *(const short8*)&T[rowb][kt * 32 + lg * 8];
    f32x4 acc2[8];
#pragma unroll
    for (int nt = 0; nt < 8; nt++) {
      float4 bv = *(const float4*)&bb[nt * 16 + lg * 4];
      acc2[nt][0] = bv.x; acc2[nt][1] = bv.y; acc2[nt][2] = bv.z; acc2[nt][3] = bv.w;
    }
#pragma unroll
    for (int kt = 0; kt < 4; kt++)
#pragma unroll
      for (int nt = 0; nt < 8; nt++)
        acc2[nt] = __builtin_amdgcn_mfma_f32_16x16x32_bf16(w2r[nt][kt], tfr[kt],
                                                           acc2[nt], 0, 0, 0);

#pragma unroll
    for (int nt = 0; nt < 8; nt++) {
      float v[4];
#pragma unroll
      for (int r = 0; r < 4; r++) v[r] = fmaxf(acc2[nt][r], 0.f);
      if (ok)
        *(uint2*)&C[(size_t)row * 128 + nt * 16 + lg * 4] =
            make_uint2(pack2(v[0], v[1]), pack2(v[2], v[3]));
#pragma unroll
      for (int r = 0; r < 4; r++) {
        float s_ = ok ? v[r] : 0.f;
        float q_ = s_ * s_;
        s_ += __shfl_xor(s_, 1);  q_ += __shfl_xor(q_, 1);
        s_ += __shfl_xor(s_, 2);  q_ += __shfl_xor(q_, 2);
        s_ += __shfl_xor(s_, 4);  q_ += __shfl_xor(q_, 4);
        s_ += __shfl_xor(s_, 8);  q_ += __shfl_xor(q_, 8);
        if (lr == 0) {
          atomicAdd(&sS[nt * 16 + lg * 4 + r], s_);
          atomicAdd(&sQ[nt * 16 + lg * 4 + r], q_);
        }
      }
    }
    __syncthreads();  // T consumed + stats settled before next tile
  }
  if (tid < 128) {
    atomicAdd(&stats[tid], sS[tid]);
    atomicAdd(&stats[128 + tid], sQ[tid]);
  }
}

// ---------------- fused layer 3: gather + GEMM1 + 128x2 out + stats -------
__global__ __launch_bounds__(256, 2) void gin_fused_out(
    const uint* __restrict__ X, const int* __restrict__ rp,
    const int* __restrict__ cols, const float* __restrict__ sums,
    const float* __restrict__ gamma, const float* __restrict__ beta,
    const uint4* __restrict__ pWa, const float* __restrict__ ba,
    const float* __restrict__ W5b, const float* __restrict__ b5b,
    float* __restrict__ O, float* __restrict__ st3) {
  __shared__ uint4 W1l[2048];
  __shared__ ushort T[64][136];
  __shared__ uint Ht[64][68];
  __shared__ float Wc[256];
  __shared__ float red[4][4];
  int tid = threadIdx.x;
#pragma unroll
  for (int i = 0; i < 8; i++) W1l[tid + i * 256] = pWa[tid + i * 256];
  Wc[tid] = W5b[tid];
  int wv = tid >> 6, l = tid & 63, lr = l & 15, lg = l >> 4;
  int rowb = wv * 16 + lr;
  int row0 = blockIdx.x * MLP_ROWS;

  int f0 = l * 2;
  float m0 = sums[f0] * (1.f / Nn), m1 = sums[f0 + 1] * (1.f / Nn);
  float vv0 = sums[128 + f0] * (1.f / Nn) - m0 * m0;
  float vv1 = sums[128 + f0 + 1] * (1.f / Nn) - m1 * m1;
  float A0 = rsqrtf(vv0 + 1e-5f) * gamma[f0];
  float A1 = rsqrtf(vv1 + 1e-5f) * gamma[f0 + 1];
  float B0 = beta[f0] - m0 * A0;
  float B1 = beta[f0 + 1] - m1 * A1;

  float so0 = 0.f, so1 = 0.f, sq0 = 0.f, sq1 = 0.f;
  for (int rt = 0; rt < MLP_ROWS / 64; rt++) {
    int base = row0 + rt * 64;
    for (int i = 0; i < 16; i++) {
      int node = base + wv * 16 + i;
      if (node < Nn) {
        gather_node<true>(X, rp, cols, node, l, A0, A1, B0, B1, &Ht[wv * 16 + i][0]);
      } else {
        Ht[wv * 16 + i][l] = 0;
      }
    }
    __syncthreads();

    short8 afr[4];
#pragma unroll
    for (int kt = 0; kt < 4; kt++)
      afr[kt] = *(const short8*)&Ht[rowb][kt * 16 + lg * 4];
    f32x4 acc[8];
#pragma unroll
    for (int nt = 0; nt < 8; nt++) {
      float4 bv = *(const float4*)&ba[nt * 16 + lg * 4];
      acc[nt][0] = bv.x; acc[nt][1] = bv.y; acc[nt][2] = bv.z; acc[nt][3] = bv.w;
    }
#pragma unroll
    for (int kt = 0; kt < 4; kt++)
#pragma unroll
      for (int nt = 0; nt < 8; nt++) {
        short8 w1 = *(const short8*)&W1l[(nt * 4 + kt) * 64 + l];
        acc[nt] = __builtin_amdgcn_mfma_f32_16x16x32_bf16(w1, afr[kt], acc[nt],
                                                          0, 0, 0);
      }
#pragma unroll
    for (int nt = 0; nt < 8; nt++) {
      float v0 = fmaxf(acc[nt][0], 0.f), v1 = fmaxf(acc[nt][1], 0.f);
      float v2 = fmaxf(acc[nt][2], 0.f), v3 = fmaxf(acc[nt][3], 0.f);
      *(uint2*)&T[rowb][nt * 16 + lg * 4] = make_uint2(pack2(v0, v1), pack2(v2, v3));
    }
    __syncthreads();

    int row = base + rowb;
    bool ok = row < Nn;
    float a0 = 0.f, a1 = 0.f;
    int ks = lg * 32;
#pragma unroll
    for (int q = 0; q < 4; q++) {
      uint4 u = *(const uint4*)&T[rowb][ks + q * 8];
      uint uu[4] = {u.x, u.y, u.z, u.w};
#pragma unroll
      for (int h = 0; h < 4; h++) {
        int k = ks + q * 8 + h * 2;
        float e0 = bflo(uu[h]), e1 = bfhi(uu[h]);
        a0 = fmaf(e0, Wc[k * 2 + 0], a0);
        a1 = fmaf(e0, Wc[k * 2 + 1], a1);
        a0 = fmaf(e1, Wc[k * 2 + 2], a0);
        a1 = fmaf(e1, Wc[k * 2 + 3], a1);
      }
    }
    a0 += __shfl_xor(a0, 16);
    a0 += __shfl_xor(a0, 32);
    a1 += __shfl_xor(a1, 16);
    a1 += __shfl_xor(a1, 32);
    if (l < 16 && ok) {
      float o0 = fmaxf(a0 + b5b[0], 0.f);
      float o1 = fmaxf(a1 + b5b[1], 0.f);
      *(float2*)&O[(size_t)row * 2] = make_float2(o0, o1);
      so0 += o0; sq0 += o0 * o0;
      so1 += o1; sq1 += o1 * o1;
    }
    __syncthreads();
  }
#pragma unroll
  for (int off = 1; off < 64; off <<= 1) {
    so0 += __shfl_xor(so0, off);
    sq0 += __shfl_xor(sq0, off);
    so1 += __shfl_xor(so1, off);
    sq1 += __shfl_xor(sq1, off);
  }
  if (l == 0) {
    red[wv][0] = so0; red[wv][1] = so1; red[wv][2] = sq0; red[wv][3] = sq1;
  }
  __syncthreads();
  if (tid < 4) {
    float t = red[0][tid] + red[1][tid] + red[2][tid] + red[3][tid];
    atomicAdd(&st3[tid], t);
  }
}

__global__ __launch_bounds__(256) void bn_apply2(const float* __restrict__ H,
                                                 const float* __restrict__ sums,
                                                 const float* __restrict__ gamma,
                                                 const float* __restrict__ beta,
                                                 float* __restrict__ Out, int nRows) {
  int idx = blockIdx.x * 256 + threadIdx.x;
  if (idx >= nRows * 2) return;
  int f = idx & 1;
  float mean = sums[f] * (1.0f / Nn);
  float var = sums[2 + f] * (1.0f / Nn) - mean * mean;
  float inv = rsqrtf(var + 1e-5f);
  Out[idx] = (H[idx] - mean) * inv * gamma[f] + beta[f];
}

extern "C" void kernel_launch(void* const* d_in, const int* in_sizes, int n_in,
                              void* d_out, int out_size, void* d_ws, size_t ws_size,
                              hipStream_t stream) {
  const float* x = (const float*)d_in[0];
  const int* src = (const int*)d_in[1];
  const int* dst = src + Ne;
  const float* W1a = (const float*)d_in[2];
  const float* b1a = (const float*)d_in[3];
  const float* W1b = (const float*)d_in[4];
  const float* b1b = (const float*)d_in[5];
  const float* g1 = (const float*)d_in[6];
  const float* be1 = (const float*)d_in[7];
  const float* W2a = (const float*)d_in[8];
  const float* b2a = (const float*)d_in[9];
  const float* W2b = (const float*)d_in[10];
  const float* b2b = (const float*)d_in[11];
  const float* g2 = (const float*)d_in[12];
  const float* be2 = (const float*)d_in[13];
  const float* W5a = (const float*)d_in[14];
  const float* b5a = (const float*)d_in[15];
  const float* W5b = (const float*)d_in[16];
  const float* b5b = (const float*)d_in[17];
  const float* g5 = (const float*)d_in[18];
  const float* be5 = (const float*)d_in[19];

  char* base = (char*)d_ws;
  size_t off = 0;
  auto carve = [&](size_t bytes) {
    char* p = base + off;
    off += (bytes + 255) & ~(size_t)255;
    return p;
  };
  // stats and rowptr adjacent -> single memset covers both
  float* stats = (float*)carve(520 * 4);              // 2304B after align
  int* rowptr = (int*)carve((size_t)(Nn + 1) * 4);
  float* o2buf = (float*)carve((size_t)Nn * 2 * 4);
  int* cur = (int*)carve((size_t)Nn * 4);
  int* cols = (int*)carve((size_t)Ne * 4);
  int* bsum = (int*)carve((size_t)SCAN_G * 4);
  ushort* xb = (ushort*)carve((size_t)Nn * 128 * 2);
  ushort* bufA = (ushort*)carve((size_t)Nn * 128 * 2);
  ushort* bufB = (ushort*)carve((size_t)Nn * 128 * 2);
  ushort* pw = (ushort*)carve((size_t)5 * 16384 * 2);
  float* st1 = stats, *st2 = stats + 256, *st3 = stats + 512;

  size_t zeroBytes = ((char*)(rowptr + Nn + 1)) - ((char*)stats);
  hipMemsetAsync(stats, 0, zeroBytes, stream);

  const int eGrid = (Ne + 255) / 256;
  const int mlpGrid = (Nn + MLP_ROWS - 1) / MLP_ROWS;  // 391

  prep_all<<<CVT_B + PK_B + EH_B, 256, 0, stream>>>(
      (const float4*)x, (uint2*)xb, W1a, W1b, W2a, W2b, W5a, pw, dst, rowptr);
  scan_p1<<<SCAN_G, 1024, 0, stream>>>(rowptr, bsum);
  scan_p3m<<<SCAN_G, 1024, 0, stream>>>(rowptr, bsum, cur);
  edge_fill<<<eGrid, 256, 0, stream>>>(src, dst, cur, cols);

  const uint4* pW1a = (const uint4*)pw;
  const short8* pW1b = (const short8*)(pw + 16384);
  const uint4* pW2a = (const uint4*)(pw + 32768);
  const short8* pW2b = (const short8*)(pw + 49152);
  const uint4* pW5a = (const uint4*)(pw + 65536);

  // ---- layer 1 (no BN fold) ----
  gin_fused<false><<<mlpGrid, 256, 0, stream>>>(
      (const uint*)xb, rowptr, cols, nullptr, nullptr, nullptr, pW1a, b1a, pW1b,
      b1b, bufB, st1);
  // ---- layer 2 (fold BN1) ----
  gin_fused<true><<<mlpGrid, 256, 0, stream>>>(
      (const uint*)bufB, rowptr, cols, st1, g1, be1, pW2a, b2a, pW2b, b2b, bufA,
      st2);
  // ---- layer 3 (fold BN2, 128x2 output) ----
  gin_fused_out<<<mlpGrid, 256, 0, stream>>>((const uint*)bufA, rowptr, cols, st2,
                                             g2, be2, pW5a, b5a, W5b, b5b, o2buf,
                                             st3);
  bn_apply2<<<(Nn * 2 + 255) / 256, 256, 0, stream>>>(o2buf, st3, g5, be5,
                                                      (float*)d_out, Nn);
}

// Round 12
// 264.852 us; speedup vs baseline: 2.0128x; 2.0128x over previous
//
#include <hip/hip_runtime.h>

// GIN 3-layer forward on MI355X — round 12: revert r11 fusion (TLP collapse);
// r10 structure + merged scan + single memset + MLP occupancy 3 blocks/CU.

constexpr int Nn = 50000;
constexpr int Ne = 600000;

typedef __attribute__((ext_vector_type(8))) short short8;
typedef __attribute__((ext_vector_type(4))) float f32x4;

// ---------------- bf16 helpers -------------------------------------------
__device__ inline float bflo(uint u) { return __uint_as_float(u << 16); }
__device__ inline float bfhi(uint u) { return __uint_as_float(u & 0xffff0000u); }
__device__ inline ushort f2b(float f) {
  uint x = __float_as_uint(f);
  return (ushort)((x + 0x7fffu + ((x >> 16) & 1u)) >> 16);  // RNE, finite vals
}
__device__ inline uint pack2(float a, float b) {
  return (uint)f2b(a) | ((uint)f2b(b) << 16);
}

// ---------------- fused prep: cvt_bf16 | pack_w | edge_hist ---------------
constexpr int CVT_B = (Nn * 32) / 256;        // 6250
constexpr int PK_B = (5 * 2048) / 256;        // 40
constexpr int EH_B = (Ne + 255) / 256;        // 2344
__global__ __launch_bounds__(256) void prep_all(
    const float4* __restrict__ x4, uint2* __restrict__ xb,
    const float* __restrict__ Wa, const float* __restrict__ Wb,
    const float* __restrict__ Wc, const float* __restrict__ Wd,
    const float* __restrict__ We, ushort* __restrict__ pw,
    const int* __restrict__ dst, int* __restrict__ rp) {
  int b = blockIdx.x;
  if (b < CVT_B) {
    int i = b * 256 + threadIdx.x;
    float4 v = x4[i];
    xb[i] = make_uint2(pack2(v.x, v.y), pack2(v.z, v.w));
  } else if (b < CVT_B + PK_B) {
    int t = (b - CVT_B) * 256 + threadIdx.x;
    int mat = t >> 11;
    int r = t & 2047;
    int lane = r & 63;
    int ktnt = r >> 6;
    int kt = ktnt & 3, nt = ktnt >> 2;
    const float* W = mat == 0 ? Wa : mat == 1 ? Wb : mat == 2 ? Wc : mat == 3 ? Wd : We;
    int c = nt * 16 + (lane & 15);
    int k0 = kt * 32 + 8 * (lane >> 4);
    ushort tmp[8];
#pragma unroll
    for (int j = 0; j < 8; j++) tmp[j] = f2b(W[(size_t)(k0 + j) * 128 + c]);
    *(uint4*)&pw[(size_t)mat * 16384 + r * 8] = *(uint4*)tmp;
  } else {
    int e = (b - CVT_B - PK_B) * 256 + threadIdx.x;
    if (e < Ne) atomicAdd(&rp[dst[e] + 1], 1);
  }
}

// ---------------- CSR scan ------------------------------------------------
constexpr int SCAN_N = Nn + 1;
constexpr int SCAN_G = (SCAN_N + 1023) / 1024;  // 49

__global__ __launch_bounds__(1024) void scan_p1(int* __restrict__ rp,
                                                int* __restrict__ bsum) {
  __shared__ int wsum[16];
  __shared__ int wpre[16];
  int i = blockIdx.x * 1024 + threadIdx.x;
  int lane = threadIdx.x & 63, wv = threadIdx.x >> 6;
  int v = (i < SCAN_N) ? rp[i] : 0;
#pragma unroll
  for (int off = 1; off < 64; off <<= 1) {
    int t = __shfl_up(v, off);
    if (lane >= off) v += t;
  }
  if (lane == 63) wsum[wv] = v;
  __syncthreads();
  if (threadIdx.x == 0) {
    int acc = 0;
#pragma unroll
    for (int w = 0; w < 16; w++) {
      wpre[w] = acc;
      acc += wsum[w];
    }
    bsum[blockIdx.x] = acc;
  }
  __syncthreads();
  if (i < SCAN_N) rp[i] = v + wpre[wv];
}

// phase 2+3 merged: each block wave-reduces its prefix of bsum, adds offsets
__global__ __launch_bounds__(1024) void scan_p3m(int* __restrict__ rp,
                                                 const int* __restrict__ bsum,
                                                 int* __restrict__ cur) {
  __shared__ int off_s;
  if (threadIdx.x < 64) {
    int v = (threadIdx.x < blockIdx.x) ? bsum[threadIdx.x] : 0;  // SCAN_G<=64
#pragma unroll
    for (int o = 1; o < 64; o <<= 1) v += __shfl_xor(v, o);
    if (threadIdx.x == 0) off_s = v;
  }
  __syncthreads();
  int off = off_s;
  int i = blockIdx.x * 1024 + threadIdx.x;
  if (i < SCAN_N) {
    int v = rp[i] + off;
    rp[i] = v;
    if (i < Nn) cur[i] = v;
  }
}

__global__ __launch_bounds__(256) void edge_fill(const int* __restrict__ src,
                                                 const int* __restrict__ dst,
                                                 int* __restrict__ cur,
                                                 int* __restrict__ cols) {
  int e = blockIdx.x * 256 + threadIdx.x;
  if (e < Ne) {
    int p = atomicAdd(&cur[dst[e]], 1);
    cols[p] = src[e];
  }
}

// ---------------- gather: batched row loads via pre-fetched neighbor ids --
template <bool FOLD>
__global__ __launch_bounds__(256) void gather_bn(const uint* __restrict__ X,
                                                 const int* __restrict__ rp,
                                                 const int* __restrict__ cols,
                                                 const float* __restrict__ sums,
                                                 const float* __restrict__ gamma,
                                                 const float* __restrict__ beta,
                                                 uint* __restrict__ H) {
  int wid = (blockIdx.x * 256 + threadIdx.x) >> 6;
  if (wid >= Nn) return;
  int lane = threadIdx.x & 63;
  int f0 = lane * 2;
  float A0 = 1.f, A1 = 1.f, B0 = 0.f, B1 = 0.f;
  if (FOLD) {
    float m0 = sums[f0] * (1.f / Nn), m1 = sums[f0 + 1] * (1.f / Nn);
    float v0 = sums[128 + f0] * (1.f / Nn) - m0 * m0;
    float v1 = sums[128 + f0 + 1] * (1.f / Nn) - m1 * m1;
    A0 = rsqrtf(v0 + 1e-5f) * gamma[f0];
    A1 = rsqrtf(v1 + 1e-5f) * gamma[f0 + 1];
    B0 = beta[f0] - m0 * A0;
    B1 = beta[f0 + 1] - m1 * A1;
  }
  int p0 = rp[wid], p1 = rp[wid + 1];
  int deg = p1 - p0;
  uint su = X[(size_t)wid * 64 + lane];
  float ax = bflo(su), ay = bfhi(su);
  if (deg > 0) {
    int ci = p0 + (lane & 31);
    int cv = cols[ci < p1 ? ci : p1 - 1];
    if (deg <= 16) {
#pragma unroll
      for (int j = 0; j < 16; j++) {
        int s = __shfl(cv, j);
        uint u = X[(size_t)s * 64 + lane];
        float m = j < deg ? 1.f : 0.f;
        ax = fmaf(m, bflo(u), ax);
        ay = fmaf(m, bfhi(u), ay);
      }
    } else {
#pragma unroll
      for (int j = 0; j < 32; j++) {
        int s = __shfl(cv, j);
        uint u = X[(size_t)s * 64 + lane];
        float m = j < deg ? 1.f : 0.f;
        ax = fmaf(m, bflo(u), ax);
        ay = fmaf(m, bfhi(u), ay);
      }
      for (int p = p0 + 32; p < p1; ++p) {  // rare tail (deg > 32)
        int s = __builtin_amdgcn_readfirstlane(cols[p]);
        uint u = X[(size_t)s * 64 + lane];
        ax += bflo(u);
        ay += bfhi(u);
      }
    }
  }
  float cnt = (float)(deg + 1);
  float ox = FOLD ? A0 * ax + cnt * B0 : ax;
  float oy = FOLD ? A1 * ay + cnt * B1 : ay;
  H[(size_t)wid * 64 + lane] = pack2(ox, oy);
}

// ---------------- fused MLP: W1 via LDS ds_reads, W2 pinned in regs -------
constexpr int MLP_ROWS = 128;  // 2 row-tiles of 64
__global__ __launch_bounds__(256, 3) void gin_mlp(const ushort* __restrict__ A,
                                                  const uint4* __restrict__ pWa,
                                                  const float* __restrict__ ba,
                                                  const short8* __restrict__ pWb,
                                                  const float* __restrict__ bb,
                                                  ushort* __restrict__ C,
                                                  float* __restrict__ stats) {
  __shared__ uint4 W1l[2048];     // 32KB: W1 fragments, linear copy of pWa
  __shared__ ushort T[64][136];   // 17.4KB intermediate bounce
  __shared__ float sS[128], sQ[128];
  int tid = threadIdx.x;
#pragma unroll
  for (int i = 0; i < 8; i++) W1l[tid + i * 256] = pWa[tid + i * 256];
  if (tid < 128) {
    sS[tid] = 0.f;
    sQ[tid] = 0.f;
  }
  int wv = tid >> 6, l = tid & 63, lr = l & 15, lg = l >> 4;
  int rowb = wv * 16 + lr;
  int row0 = blockIdx.x * MLP_ROWS;

  short8 w2r[8][4];
#pragma unroll
  for (int nt = 0; nt < 8; nt++)
#pragma unroll
    for (int kt = 0; kt < 4; kt++) w2r[nt][kt] = pWb[(nt * 4 + kt) * 64 + l];
  __builtin_amdgcn_sched_barrier(0);
  __syncthreads();

  for (int rt = 0; rt < MLP_ROWS / 64; rt++) {
    int row = row0 + rt * 64 + rowb;
    bool ok = row < Nn;

    short8 afr[4];
#pragma unroll
    for (int kt = 0; kt < 4; kt++) {
      afr[kt] = short8{};
      if (ok) afr[kt] = *(const short8*)(A + (size_t)row * 128 + kt * 32 + lg * 8);
    }
    f32x4 acc[8];
#pragma unroll
    for (int nt = 0; nt < 8; nt++) {
      float4 bv = *(const float4*)&ba[nt * 16 + lg * 4];
      acc[nt][0] = bv.x; acc[nt][1] = bv.y; acc[nt][2] = bv.z; acc[nt][3] = bv.w;
    }
#pragma unroll
    for (int kt = 0; kt < 4; kt++)
#pragma unroll
      for (int nt = 0; nt < 8; nt++) {
        short8 w1 = *(const short8*)&W1l[(nt * 4 + kt) * 64 + l];
        acc[nt] = __builtin_amdgcn_mfma_f32_16x16x32_bf16(w1, afr[kt], acc[nt],
                                                          0, 0, 0);
      }
#pragma unroll
    for (int nt = 0; nt < 8; nt++) {
      float v0 = fmaxf(acc[nt][0], 0.f), v1 = fmaxf(acc[nt][1], 0.f);
      float v2 = fmaxf(acc[nt][2], 0.f), v3 = fmaxf(acc[nt][3], 0.f);
      *(uint2*)&T[rowb][nt * 16 + lg * 4] = make_uint2(pack2(v0, v1), pack2(v2, v3));
    }
    __syncthreads();

    short8 tfr[4];
#pragma unroll
    for (int kt = 0; kt < 4; kt++) tfr[kt] = *(const short8*)&T[rowb][kt * 32 + lg * 8];
    f32x4 acc2[8];
#pragma unroll
    for (int nt = 0; nt < 8; nt++) {
      float4 bv = *(const float4*)&bb[nt * 16 + lg * 4];
      acc2[nt][0] = bv.x; acc2[nt][1] = bv.y; acc2[nt][2] = bv.z; acc2[nt][3] = bv.w;
    }
#pragma unroll
    for (int kt = 0; kt < 4; kt++)
#pragma unroll
      for (int nt = 0; nt < 8; nt++)
        acc2[nt] = __builtin_amdgcn_mfma_f32_16x16x32_bf16(w2r[nt][kt], tfr[kt],
                                                           acc2[nt], 0, 0, 0);

#pragma unroll
    for (int nt = 0; nt < 8; nt++) {
      float v[4];
#pragma unroll
      for (int r = 0; r < 4; r++) v[r] = fmaxf(acc2[nt][r], 0.f);
      if (ok)
        *(uint2*)&C[(size_t)row * 128 + nt * 16 + lg * 4] =
            make_uint2(pack2(v[0], v[1]), pack2(v[2], v[3]));
#pragma unroll
      for (int r = 0; r < 4; r++) {
        float s_ = ok ? v[r] : 0.f;
        float q_ = s_ * s_;
        s_ += __shfl_xor(s_, 1);  q_ += __shfl_xor(q_, 1);
        s_ += __shfl_xor(s_, 2);  q_ += __shfl_xor(q_, 2);
        s_ += __shfl_xor(s_, 4);  q_ += __shfl_xor(q_, 4);
        s_ += __shfl_xor(s_, 8);  q_ += __shfl_xor(q_, 8);
        if (lr == 0) {
          atomicAdd(&sS[nt * 16 + lg * 4 + r], s_);
          atomicAdd(&sQ[nt * 16 + lg * 4 + r], q_);
        }
      }
    }
    __syncthreads();
  }
  if (tid < 128) {
    atomicAdd(&stats[tid], sS[tid]);
    atomicAdd(&stats[128 + tid], sQ[tid]);
  }
}

// ---------------- layer-3 fused MLP: W5a via LDS, tiny out2 stage ---------
__global__ __launch_bounds__(256, 3) void gin_mlp_out(const ushort* __restrict__ A,
                                                      const uint4* __restrict__ pWa,
                                                      const float* __restrict__ ba,
                                                      const float* __restrict__ W5b,
                                                      const float* __restrict__ b5b,
                                                      float* __restrict__ O,
                                                      float* __restrict__ st3) {
  __shared__ uint4 W1l[2048];  // 32KB W5a fragments
  __shared__ ushort T[64][136];
  __shared__ float Wc[256];
  __shared__ float red[4][4];
  int tid = threadIdx.x;
#pragma unroll
  for (int i = 0; i < 8; i++) W1l[tid + i * 256] = pWa[tid + i * 256];
  Wc[tid] = W5b[tid];
  int wv = tid >> 6, l = tid & 63, lr = l & 15, lg = l >> 4;
  int rowb = wv * 16 + lr;
  int row0 = blockIdx.x * MLP_ROWS;
  __syncthreads();

  float so0 = 0.f, so1 = 0.f, sq0 = 0.f, sq1 = 0.f;
  for (int rt = 0; rt < MLP_ROWS / 64; rt++) {
    int row = row0 + rt * 64 + rowb;
    bool ok = row < Nn;

    short8 afr[4];
#pragma unroll
    for (int kt = 0; kt < 4; kt++) {
      afr[kt] = short8{};
      if (ok) afr[kt] = *(const short8*)(A + (size_t)row * 128 + kt * 32 + lg * 8);
    }
    f32x4 acc[8];
#pragma unroll
    for (int nt = 0; nt < 8; nt++) {
      float4 bv = *(const float4*)&ba[nt * 16 + lg * 4];
      acc[nt][0] = bv.x; acc[nt][1] = bv.y; acc[nt][2] = bv.z; acc[nt][3] = bv.w;
    }
#pragma unroll
    for (int kt = 0; kt < 4; kt++)
#pragma unroll
      for (int nt = 0; nt < 8; nt++) {
        short8 w1 = *(const short8*)&W1l[(nt * 4 + kt) * 64 + l];
        acc[nt] = __builtin_amdgcn_mfma_f32_16x16x32_bf16(w1, afr[kt], acc[nt],
                                                          0, 0, 0);
      }
#pragma unroll
    for (int nt = 0; nt < 8; nt++) {
      float v0 = fmaxf(acc[nt][0], 0.f), v1 = fmaxf(acc[nt][1], 0.f);
      float v2 = fmaxf(acc[nt][2], 0.f), v3 = fmaxf(acc[nt][3], 0.f);
      *(uint2*)&T[rowb][nt * 16 + lg * 4] = make_uint2(pack2(v0, v1), pack2(v2, v3));
    }
    __syncthreads();

    float a0 = 0.f, a1 = 0.f;
    int ks = lg * 32;
#pragma unroll
    for (int q = 0; q < 4; q++) {
      uint4 u = *(const uint4*)&T[rowb][ks + q * 8];
      uint uu[4] = {u.x, u.y, u.z, u.w};
#pragma unroll
      for (int h = 0; h < 4; h++) {
        int k = ks + q * 8 + h * 2;
        float e0 = bflo(uu[h]), e1 = bfhi(uu[h]);
        a0 = fmaf(e0, Wc[k * 2 + 0], a0);
        a1 = fmaf(e0, Wc[k * 2 + 1], a1);
        a0 = fmaf(e1, Wc[k * 2 + 2], a0);
        a1 = fmaf(e1, Wc[k * 2 + 3], a1);
      }
    }
    a0 += __shfl_xor(a0, 16);
    a0 += __shfl_xor(a0, 32);
    a1 += __shfl_xor(a1, 16);
    a1 += __shfl_xor(a1, 32);
    if (l < 16 && ok) {
      float o0 = fmaxf(a0 + b5b[0], 0.f);
      float o1 = fmaxf(a1 + b5b[1], 0.f);
      *(float2*)&O[(size_t)row * 2] = make_float2(o0, o1);
      so0 += o0; sq0 += o0 * o0;
      so1 += o1; sq1 += o1 * o1;
    }
    __syncthreads();
  }
#pragma unroll
  for (int off = 1; off < 64; off <<= 1) {
    so0 += __shfl_xor(so0, off);
    sq0 += __shfl_xor(sq0, off);
    so1 += __shfl_xor(so1, off);
    sq1 += __shfl_xor(sq1, off);
  }
  if (l == 0) {
    red[wv][0] = so0; red[wv][1] = so1; red[wv][2] = sq0; red[wv][3] = sq1;
  }
  __syncthreads();
  if (tid < 4) {
    float t = red[0][tid] + red[1][tid] + red[2][tid] + red[3][tid];
    atomicAdd(&st3[tid], t);
  }
}

__global__ __launch_bounds__(256) void bn_apply2(const float* __restrict__ H,
                                                 const float* __restrict__ sums,
                                                 const float* __restrict__ gamma,
                                                 const float* __restrict__ beta,
                                                 float* __restrict__ Out, int nRows) {
  int idx = blockIdx.x * 256 + threadIdx.x;
  if (idx >= nRows * 2) return;
  int f = idx & 1;
  float mean = sums[f] * (1.0f / Nn);
  float var = sums[2 + f] * (1.0f / Nn) - mean * mean;
  float inv = rsqrtf(var + 1e-5f);
  Out[idx] = (H[idx] - mean) * inv * gamma[f] + beta[f];
}

extern "C" void kernel_launch(void* const* d_in, const int* in_sizes, int n_in,
                              void* d_out, int out_size, void* d_ws, size_t ws_size,
                              hipStream_t stream) {
  const float* x = (const float*)d_in[0];
  const int* src = (const int*)d_in[1];
  const int* dst = src + Ne;
  const float* W1a = (const float*)d_in[2];
  const float* b1a = (const float*)d_in[3];
  const float* W1b = (const float*)d_in[4];
  const float* b1b = (const float*)d_in[5];
  const float* g1 = (const float*)d_in[6];
  const float* be1 = (const float*)d_in[7];
  const float* W2a = (const float*)d_in[8];
  const float* b2a = (const float*)d_in[9];
  const float* W2b = (const float*)d_in[10];
  const float* b2b = (const float*)d_in[11];
  const float* g2 = (const float*)d_in[12];
  const float* be2 = (const float*)d_in[13];
  const float* W5a = (const float*)d_in[14];
  const float* b5a = (const float*)d_in[15];
  const float* W5b = (const float*)d_in[16];
  const float* b5b = (const float*)d_in[17];
  const float* g5 = (const float*)d_in[18];
  const float* be5 = (const float*)d_in[19];

  char* base = (char*)d_ws;
  size_t off = 0;
  auto carve = [&](size_t bytes) {
    char* p = base + off;
    off += (bytes + 255) & ~(size_t)255;
    return p;
  };
  // stats and rowptr adjacent -> single memset covers both
  float* stats = (float*)carve(520 * 4);
  int* rowptr = (int*)carve((size_t)(Nn + 1) * 4);
  float* o2buf = (float*)carve((size_t)Nn * 2 * 4);
  int* cur = (int*)carve((size_t)Nn * 4);
  int* cols = (int*)carve((size_t)Ne * 4);
  int* bsum = (int*)carve((size_t)SCAN_G * 4);
  ushort* xb = (ushort*)carve((size_t)Nn * 128 * 2);
  ushort* bufA = (ushort*)carve((size_t)Nn * 128 * 2);
  ushort* bufB = (ushort*)carve((size_t)Nn * 128 * 2);
  ushort* pw = (ushort*)carve((size_t)5 * 16384 * 2);
  float* st1 = stats, *st2 = stats + 256, *st3 = stats + 512;

  size_t zeroBytes = ((char*)(rowptr + Nn + 1)) - ((char*)stats);
  hipMemsetAsync(stats, 0, zeroBytes, stream);

  const int eGrid = (Ne + 255) / 256;
  const int gatherGrid = (Nn * 64 + 255) / 256;
  const int mlpGrid = (Nn + MLP_ROWS - 1) / MLP_ROWS;  // 391

  prep_all<<<CVT_B + PK_B + EH_B, 256, 0, stream>>>(
      (const float4*)x, (uint2*)xb, W1a, W1b, W2a, W2b, W5a, pw, dst, rowptr);
  scan_p1<<<SCAN_G, 1024, 0, stream>>>(rowptr, bsum);
  scan_p3m<<<SCAN_G, 1024, 0, stream>>>(rowptr, bsum, cur);
  edge_fill<<<eGrid, 256, 0, stream>>>(src, dst, cur, cols);

  const uint4* pW1a = (const uint4*)pw;
  const short8* pW1b = (const short8*)(pw + 16384);
  const uint4* pW2a = (const uint4*)(pw + 32768);
  const short8* pW2b = (const short8*)(pw + 49152);
  const uint4* pW5a = (const uint4*)(pw + 65536);

  // ---- layer 1 ----
  gather_bn<false><<<gatherGrid, 256, 0, stream>>>((const uint*)xb, rowptr, cols,
                                                   nullptr, nullptr, nullptr,
                                                   (uint*)bufA);
  gin_mlp<<<mlpGrid, 256, 0, stream>>>(bufA, pW1a, b1a, pW1b, b1b, bufB, st1);

  // ---- layer 2 ----
  gather_bn<true><<<gatherGrid, 256, 0, stream>>>((const uint*)bufB, rowptr, cols, st1,
                                                  g1, be1, (uint*)bufA);
  gin_mlp<<<mlpGrid, 256, 0, stream>>>(bufA, pW2a, b2a, pW2b, b2b, bufB, st2);

  // ---- layer 3 ----
  gather_bn<true><<<gatherGrid, 256, 0, stream>>>((const uint*)bufB, rowptr, cols, st2,
                                                  g2, be2, (uint*)bufA);
  gin_mlp_out<<<mlpGrid, 256, 0, stream>>>(bufA, pW5a, b5a, W5b, b5b, o2buf, st3);
  bn_apply2<<<(Nn * 2 + 255) / 256, 256, 0, stream>>>(o2buf, st3, g5, be5,
                                                      (float*)d_out, Nn);
}

// Round 13
// 228.219 us; speedup vs baseline: 2.3359x; 1.1605x over previous
//
#include <hip/hip_runtime.h>

// GIN 3-layer forward on MI355X — round 13: revert MLP to launch_bounds(256,2)
// (the (256,3) VGPR cap ~85 caused spill); keep merged scan + single memset.

constexpr int Nn = 50000;
constexpr int Ne = 600000;

typedef __attribute__((ext_vector_type(8))) short short8;
typedef __attribute__((ext_vector_type(4))) float f32x4;

// ---------------- bf16 helpers -------------------------------------------
__device__ inline float bflo(uint u) { return __uint_as_float(u << 16); }
__device__ inline float bfhi(uint u) { return __uint_as_float(u & 0xffff0000u); }
__device__ inline ushort f2b(float f) {
  uint x = __float_as_uint(f);
  return (ushort)((x + 0x7fffu + ((x >> 16) & 1u)) >> 16);  // RNE, finite vals
}
__device__ inline uint pack2(float a, float b) {
  return (uint)f2b(a) | ((uint)f2b(b) << 16);
}

// ---------------- fused prep: cvt_bf16 | pack_w | edge_hist ---------------
constexpr int CVT_B = (Nn * 32) / 256;        // 6250
constexpr int PK_B = (5 * 2048) / 256;        // 40
constexpr int EH_B = (Ne + 255) / 256;        // 2344
__global__ __launch_bounds__(256) void prep_all(
    const float4* __restrict__ x4, uint2* __restrict__ xb,
    const float* __restrict__ Wa, const float* __restrict__ Wb,
    const float* __restrict__ Wc, const float* __restrict__ Wd,
    const float* __restrict__ We, ushort* __restrict__ pw,
    const int* __restrict__ dst, int* __restrict__ rp) {
  int b = blockIdx.x;
  if (b < CVT_B) {
    int i = b * 256 + threadIdx.x;
    float4 v = x4[i];
    xb[i] = make_uint2(pack2(v.x, v.y), pack2(v.z, v.w));
  } else if (b < CVT_B + PK_B) {
    int t = (b - CVT_B) * 256 + threadIdx.x;
    int mat = t >> 11;
    int r = t & 2047;
    int lane = r & 63;
    int ktnt = r >> 6;
    int kt = ktnt & 3, nt = ktnt >> 2;
    const float* W = mat == 0 ? Wa : mat == 1 ? Wb : mat == 2 ? Wc : mat == 3 ? Wd : We;
    int c = nt * 16 + (lane & 15);
    int k0 = kt * 32 + 8 * (lane >> 4);
    ushort tmp[8];
#pragma unroll
    for (int j = 0; j < 8; j++) tmp[j] = f2b(W[(size_t)(k0 + j) * 128 + c]);
    *(uint4*)&pw[(size_t)mat * 16384 + r * 8] = *(uint4*)tmp;
  } else {
    int e = (b - CVT_B - PK_B) * 256 + threadIdx.x;
    if (e < Ne) atomicAdd(&rp[dst[e] + 1], 1);
  }
}

// ---------------- CSR scan ------------------------------------------------
constexpr int SCAN_N = Nn + 1;
constexpr int SCAN_G = (SCAN_N + 1023) / 1024;  // 49

__global__ __launch_bounds__(1024) void scan_p1(int* __restrict__ rp,
                                                int* __restrict__ bsum) {
  __shared__ int wsum[16];
  __shared__ int wpre[16];
  int i = blockIdx.x * 1024 + threadIdx.x;
  int lane = threadIdx.x & 63, wv = threadIdx.x >> 6;
  int v = (i < SCAN_N) ? rp[i] : 0;
#pragma unroll
  for (int off = 1; off < 64; off <<= 1) {
    int t = __shfl_up(v, off);
    if (lane >= off) v += t;
  }
  if (lane == 63) wsum[wv] = v;
  __syncthreads();
  if (threadIdx.x == 0) {
    int acc = 0;
#pragma unroll
    for (int w = 0; w < 16; w++) {
      wpre[w] = acc;
      acc += wsum[w];
    }
    bsum[blockIdx.x] = acc;
  }
  __syncthreads();
  if (i < SCAN_N) rp[i] = v + wpre[wv];
}

// phase 2+3 merged: each block wave-reduces its prefix of bsum, adds offsets
__global__ __launch_bounds__(1024) void scan_p3m(int* __restrict__ rp,
                                                 const int* __restrict__ bsum,
                                                 int* __restrict__ cur) {
  __shared__ int off_s;
  if (threadIdx.x < 64) {
    int v = (threadIdx.x < blockIdx.x) ? bsum[threadIdx.x] : 0;  // SCAN_G<=64
#pragma unroll
    for (int o = 1; o < 64; o <<= 1) v += __shfl_xor(v, o);
    if (threadIdx.x == 0) off_s = v;
  }
  __syncthreads();
  int off = off_s;
  int i = blockIdx.x * 1024 + threadIdx.x;
  if (i < SCAN_N) {
    int v = rp[i] + off;
    rp[i] = v;
    if (i < Nn) cur[i] = v;
  }
}

__global__ __launch_bounds__(256) void edge_fill(const int* __restrict__ src,
                                                 const int* __restrict__ dst,
                                                 int* __restrict__ cur,
                                                 int* __restrict__ cols) {
  int e = blockIdx.x * 256 + threadIdx.x;
  if (e < Ne) {
    int p = atomicAdd(&cur[dst[e]], 1);
    cols[p] = src[e];
  }
}

// ---------------- gather: batched row loads via pre-fetched neighbor ids --
template <bool FOLD>
__global__ __launch_bounds__(256) void gather_bn(const uint* __restrict__ X,
                                                 const int* __restrict__ rp,
                                                 const int* __restrict__ cols,
                                                 const float* __restrict__ sums,
                                                 const float* __restrict__ gamma,
                                                 const float* __restrict__ beta,
                                                 uint* __restrict__ H) {
  int wid = (blockIdx.x * 256 + threadIdx.x) >> 6;
  if (wid >= Nn) return;
  int lane = threadIdx.x & 63;
  int f0 = lane * 2;
  float A0 = 1.f, A1 = 1.f, B0 = 0.f, B1 = 0.f;
  if (FOLD) {
    float m0 = sums[f0] * (1.f / Nn), m1 = sums[f0 + 1] * (1.f / Nn);
    float v0 = sums[128 + f0] * (1.f / Nn) - m0 * m0;
    float v1 = sums[128 + f0 + 1] * (1.f / Nn) - m1 * m1;
    A0 = rsqrtf(v0 + 1e-5f) * gamma[f0];
    A1 = rsqrtf(v1 + 1e-5f) * gamma[f0 + 1];
    B0 = beta[f0] - m0 * A0;
    B1 = beta[f0 + 1] - m1 * A1;
  }
  int p0 = rp[wid], p1 = rp[wid + 1];
  int deg = p1 - p0;
  uint su = X[(size_t)wid * 64 + lane];
  float ax = bflo(su), ay = bfhi(su);
  if (deg > 0) {
    int ci = p0 + (lane & 31);
    int cv = cols[ci < p1 ? ci : p1 - 1];
    if (deg <= 16) {
#pragma unroll
      for (int j = 0; j < 16; j++) {
        int s = __shfl(cv, j);
        uint u = X[(size_t)s * 64 + lane];
        float m = j < deg ? 1.f : 0.f;
        ax = fmaf(m, bflo(u), ax);
        ay = fmaf(m, bfhi(u), ay);
      }
    } else {
#pragma unroll
      for (int j = 0; j < 32; j++) {
        int s = __shfl(cv, j);
        uint u = X[(size_t)s * 64 + lane];
        float m = j < deg ? 1.f : 0.f;
        ax = fmaf(m, bflo(u), ax);
        ay = fmaf(m, bfhi(u), ay);
      }
      for (int p = p0 + 32; p < p1; ++p) {  // rare tail (deg > 32)
        int s = __builtin_amdgcn_readfirstlane(cols[p]);
        uint u = X[(size_t)s * 64 + lane];
        ax += bflo(u);
        ay += bfhi(u);
      }
    }
  }
  float cnt = (float)(deg + 1);
  float ox = FOLD ? A0 * ax + cnt * B0 : ax;
  float oy = FOLD ? A1 * ay + cnt * B1 : ay;
  H[(size_t)wid * 64 + lane] = pack2(ox, oy);
}

// ---------------- fused MLP: W1 via LDS ds_reads, W2 pinned in regs -------
constexpr int MLP_ROWS = 128;  // 2 row-tiles of 64
__global__ __launch_bounds__(256, 2) void gin_mlp(const ushort* __restrict__ A,
                                                  const uint4* __restrict__ pWa,
                                                  const float* __restrict__ ba,
                                                  const short8* __restrict__ pWb,
                                                  const float* __restrict__ bb,
                                                  ushort* __restrict__ C,
                                                  float* __restrict__ stats) {
  __shared__ uint4 W1l[2048];     // 32KB: W1 fragments, linear copy of pWa
  __shared__ ushort T[64][136];   // 17.4KB intermediate bounce
  __shared__ float sS[128], sQ[128];
  int tid = threadIdx.x;
#pragma unroll
  for (int i = 0; i < 8; i++) W1l[tid + i * 256] = pWa[tid + i * 256];
  if (tid < 128) {
    sS[tid] = 0.f;
    sQ[tid] = 0.f;
  }
  int wv = tid >> 6, l = tid & 63, lr = l & 15, lg = l >> 4;
  int rowb = wv * 16 + lr;
  int row0 = blockIdx.x * MLP_ROWS;

  short8 w2r[8][4];
#pragma unroll
  for (int nt = 0; nt < 8; nt++)
#pragma unroll
    for (int kt = 0; kt < 4; kt++) w2r[nt][kt] = pWb[(nt * 4 + kt) * 64 + l];
  __builtin_amdgcn_sched_barrier(0);
  __syncthreads();

  for (int rt = 0; rt < MLP_ROWS / 64; rt++) {
    int row = row0 + rt * 64 + rowb;
    bool ok = row < Nn;

    short8 afr[4];
#pragma unroll
    for (int kt = 0; kt < 4; kt++) {
      afr[kt] = short8{};
      if (ok) afr[kt] = *(const short8*)(A + (size_t)row * 128 + kt * 32 + lg * 8);
    }
    f32x4 acc[8];
#pragma unroll
    for (int nt = 0; nt < 8; nt++) {
      float4 bv = *(const float4*)&ba[nt * 16 + lg * 4];
      acc[nt][0] = bv.x; acc[nt][1] = bv.y; acc[nt][2] = bv.z; acc[nt][3] = bv.w;
    }
#pragma unroll
    for (int kt = 0; kt < 4; kt++)
#pragma unroll
      for (int nt = 0; nt < 8; nt++) {
        short8 w1 = *(const short8*)&W1l[(nt * 4 + kt) * 64 + l];
        acc[nt] = __builtin_amdgcn_mfma_f32_16x16x32_bf16(w1, afr[kt], acc[nt],
                                                          0, 0, 0);
      }
#pragma unroll
    for (int nt = 0; nt < 8; nt++) {
      float v0 = fmaxf(acc[nt][0], 0.f), v1 = fmaxf(acc[nt][1], 0.f);
      float v2 = fmaxf(acc[nt][2], 0.f), v3 = fmaxf(acc[nt][3], 0.f);
      *(uint2*)&T[rowb][nt * 16 + lg * 4] = make_uint2(pack2(v0, v1), pack2(v2, v3));
    }
    __syncthreads();

    short8 tfr[4];
#pragma unroll
    for (int kt = 0; kt < 4; kt++) tfr[kt] = *(const short8*)&T[rowb][kt * 32 + lg * 8];
    f32x4 acc2[8];
#pragma unroll
    for (int nt = 0; nt < 8; nt++) {
      float4 bv = *(const float4*)&bb[nt * 16 + lg * 4];
      acc2[nt][0] = bv.x; acc2[nt][1] = bv.y; acc2[nt][2] = bv.z; acc2[nt][3] = bv.w;
    }
#pragma unroll
    for (int kt = 0; kt < 4; kt++)
#pragma unroll
      for (int nt = 0; nt < 8; nt++)
        acc2[nt] = __builtin_amdgcn_mfma_f32_16x16x32_bf16(w2r[nt][kt], tfr[kt],
                                                           acc2[nt], 0, 0, 0);

#pragma unroll
    for (int nt = 0; nt < 8; nt++) {
      float v[4];
#pragma unroll
      for (int r = 0; r < 4; r++) v[r] = fmaxf(acc2[nt][r], 0.f);
      if (ok)
        *(uint2*)&C[(size_t)row * 128 + nt * 16 + lg * 4] =
            make_uint2(pack2(v[0], v[1]), pack2(v[2], v[3]));
#pragma unroll
      for (int r = 0; r < 4; r++) {
        float s_ = ok ? v[r] : 0.f;
        float q_ = s_ * s_;
        s_ += __shfl_xor(s_, 1);  q_ += __shfl_xor(q_, 1);
        s_ += __shfl_xor(s_, 2);  q_ += __shfl_xor(q_, 2);
        s_ += __shfl_xor(s_, 4);  q_ += __shfl_xor(q_, 4);
        s_ += __shfl_xor(s_, 8);  q_ += __shfl_xor(q_, 8);
        if (lr == 0) {
          atomicAdd(&sS[nt * 16 + lg * 4 + r], s_);
          atomicAdd(&sQ[nt * 16 + lg * 4 + r], q_);
        }
      }
    }
    __syncthreads();
  }
  if (tid < 128) {
    atomicAdd(&stats[tid], sS[tid]);
    atomicAdd(&stats[128 + tid], sQ[tid]);
  }
}

// ---------------- layer-3 fused MLP: W5a via LDS, tiny out2 stage ---------
__global__ __launch_bounds__(256, 2) void gin_mlp_out(const ushort* __restrict__ A,
                                                      const uint4* __restrict__ pWa,
                                                      const float* __restrict__ ba,
                                                      const float* __restrict__ W5b,
                                                      const float* __restrict__ b5b,
                                                      float* __restrict__ O,
                                                      float* __restrict__ st3) {
  __shared__ uint4 W1l[2048];  // 32KB W5a fragments
  __shared__ ushort T[64][136];
  __shared__ float Wc[256];
  __shared__ float red[4][4];
  int tid = threadIdx.x;
#pragma unroll
  for (int i = 0; i < 8; i++) W1l[tid + i * 256] = pWa[tid + i * 256];
  Wc[tid] = W5b[tid];
  int wv = tid >> 6, l = tid & 63, lr = l & 15, lg = l >> 4;
  int rowb = wv * 16 + lr;
  int row0 = blockIdx.x * MLP_ROWS;
  __syncthreads();

  float so0 = 0.f, so1 = 0.f, sq0 = 0.f, sq1 = 0.f;
  for (int rt = 0; rt < MLP_ROWS / 64; rt++) {
    int row = row0 + rt * 64 + rowb;
    bool ok = row < Nn;

    short8 afr[4];
#pragma unroll
    for (int kt = 0; kt < 4; kt++) {
      afr[kt] = short8{};
      if (ok) afr[kt] = *(const short8*)(A + (size_t)row * 128 + kt * 32 + lg * 8);
    }
    f32x4 acc[8];
#pragma unroll
    for (int nt = 0; nt < 8; nt++) {
      float4 bv = *(const float4*)&ba[nt * 16 + lg * 4];
      acc[nt][0] = bv.x; acc[nt][1] = bv.y; acc[nt][2] = bv.z; acc[nt][3] = bv.w;
    }
#pragma unroll
    for (int kt = 0; kt < 4; kt++)
#pragma unroll
      for (int nt = 0; nt < 8; nt++) {
        short8 w1 = *(const short8*)&W1l[(nt * 4 + kt) * 64 + l];
        acc[nt] = __builtin_amdgcn_mfma_f32_16x16x32_bf16(w1, afr[kt], acc[nt],
                                                          0, 0, 0);
      }
#pragma unroll
    for (int nt = 0; nt < 8; nt++) {
      float v0 = fmaxf(acc[nt][0], 0.f), v1 = fmaxf(acc[nt][1], 0.f);
      float v2 = fmaxf(acc[nt][2], 0.f), v3 = fmaxf(acc[nt][3], 0.f);
      *(uint2*)&T[rowb][nt * 16 + lg * 4] = make_uint2(pack2(v0, v1), pack2(v2, v3));
    }
    __syncthreads();

    float a0 = 0.f, a1 = 0.f;
    int ks = lg * 32;
#pragma unroll
    for (int q = 0; q < 4; q++) {
      uint4 u = *(const uint4*)&T[rowb][ks + q * 8];
      uint uu[4] = {u.x, u.y, u.z, u.w};
#pragma unroll
      for (int h = 0; h < 4; h++) {
        int k = ks + q * 8 + h * 2;
        float e0 = bflo(uu[h]), e1 = bfhi(uu[h]);
        a0 = fmaf(e0, Wc[k * 2 + 0], a0);
        a1 = fmaf(e0, Wc[k * 2 + 1], a1);
        a0 = fmaf(e1, Wc[k * 2 + 2], a0);
        a1 = fmaf(e1, Wc[k * 2 + 3], a1);
      }
    }
    a0 += __shfl_xor(a0, 16);
    a0 += __shfl_xor(a0, 32);
    a1 += __shfl_xor(a1, 16);
    a1 += __shfl_xor(a1, 32);
    if (l < 16 && ok) {
      float o0 = fmaxf(a0 + b5b[0], 0.f);
      float o1 = fmaxf(a1 + b5b[1], 0.f);
      *(float2*)&O[(size_t)row * 2] = make_float2(o0, o1);
      so0 += o0; sq0 += o0 * o0;
      so1 += o1; sq1 += o1 * o1;
    }
    __syncthreads();
  }
#pragma unroll
  for (int off = 1; off < 64; off <<= 1) {
    so0 += __shfl_xor(so0, off);
    sq0 += __shfl_xor(sq0, off);
    so1 += __shfl_xor(so1, off);
    sq1 += __shfl_xor(sq1, off);
  }
  if (l == 0) {
    red[wv][0] = so0; red[wv][1] = so1; red[wv][2] = sq0; red[wv][3] = sq1;
  }
  __syncthreads();
  if (tid < 4) {
    float t = red[0][tid] + red[1][tid] + red[2][tid] + red[3][tid];
    atomicAdd(&st3[tid], t);
  }
}

__global__ __launch_bounds__(256) void bn_apply2(const float* __restrict__ H,
                                                 const float* __restrict__ sums,
                                                 const float* __restrict__ gamma,
                                                 const float* __restrict__ beta,
                                                 float* __restrict__ Out, int nRows) {
  int idx = blockIdx.x * 256 + threadIdx.x;
  if (idx >= nRows * 2) return;
  int f = idx & 1;
  float mean = sums[f] * (1.0f / Nn);
  float var = sums[2 + f] * (1.0f / Nn) - mean * mean;
  float inv = rsqrtf(var + 1e-5f);
  Out[idx] = (H[idx] - mean) * inv * gamma[f] + beta[f];
}

extern "C" void kernel_launch(void* const* d_in, const int* in_sizes, int n_in,
                              void* d_out, int out_size, void* d_ws, size_t ws_size,
                              hipStream_t stream) {
  const float* x = (const float*)d_in[0];
  const int* src = (const int*)d_in[1];
  const int* dst = src + Ne;
  const float* W1a = (const float*)d_in[2];
  const float* b1a = (const float*)d_in[3];
  const float* W1b = (const float*)d_in[4];
  const float* b1b = (const float*)d_in[5];
  const float* g1 = (const float*)d_in[6];
  const float* be1 = (const float*)d_in[7];
  const float* W2a = (const float*)d_in[8];
  const float* b2a = (const float*)d_in[9];
  const float* W2b = (const float*)d_in[10];
  const float* b2b = (const float*)d_in[11];
  const float* g2 = (const float*)d_in[12];
  const float* be2 = (const float*)d_in[13];
  const float* W5a = (const float*)d_in[14];
  const float* b5a = (const float*)d_in[15];
  const float* W5b = (const float*)d_in[16];
  const float* b5b = (const float*)d_in[17];
  const float* g5 = (const float*)d_in[18];
  const float* be5 = (const float*)d_in[19];

  char* base = (char*)d_ws;
  size_t off = 0;
  auto carve = [&](size_t bytes) {
    char* p = base + off;
    off += (bytes + 255) & ~(size_t)255;
    return p;
  };
  // stats and rowptr adjacent -> single memset covers both
  float* stats = (float*)carve(520 * 4);
  int* rowptr = (int*)carve((size_t)(Nn + 1) * 4);
  float* o2buf = (float*)carve((size_t)Nn * 2 * 4);
  int* cur = (int*)carve((size_t)Nn * 4);
  int* cols = (int*)carve((size_t)Ne * 4);
  int* bsum = (int*)carve((size_t)SCAN_G * 4);
  ushort* xb = (ushort*)carve((size_t)Nn * 128 * 2);
  ushort* bufA = (ushort*)carve((size_t)Nn * 128 * 2);
  ushort* bufB = (ushort*)carve((size_t)Nn * 128 * 2);
  ushort* pw = (ushort*)carve((size_t)5 * 16384 * 2);
  float* st1 = stats, *st2 = stats + 256, *st3 = stats + 512;

  size_t zeroBytes = ((char*)(rowptr + Nn + 1)) - ((char*)stats);
  hipMemsetAsync(stats, 0, zeroBytes, stream);

  const int eGrid = (Ne + 255) / 256;
  const int gatherGrid = (Nn * 64 + 255) / 256;
  const int mlpGrid = (Nn + MLP_ROWS - 1) / MLP_ROWS;  // 391

  prep_all<<<CVT_B + PK_B + EH_B, 256, 0, stream>>>(
      (const float4*)x, (uint2*)xb, W1a, W1b, W2a, W2b, W5a, pw, dst, rowptr);
  scan_p1<<<SCAN_G, 1024, 0, stream>>>(rowptr, bsum);
  scan_p3m<<<SCAN_G, 1024, 0, stream>>>(rowptr, bsum, cur);
  edge_fill<<<eGrid, 256, 0, stream>>>(src, dst, cur, cols);

  const uint4* pW1a = (const uint4*)pw;
  const short8* pW1b = (const short8*)(pw + 16384);
  const uint4* pW2a = (const uint4*)(pw + 32768);
  const short8* pW2b = (const short8*)(pw + 49152);
  const uint4* pW5a = (const uint4*)(pw + 65536);

  // ---- layer 1 ----
  gather_bn<false><<<gatherGrid, 256, 0, stream>>>((const uint*)xb, rowptr, cols,
                                                   nullptr, nullptr, nullptr,
                                                   (uint*)bufA);
  gin_mlp<<<mlpGrid, 256, 0, stream>>>(bufA, pW1a, b1a, pW1b, b1b, bufB, st1);

  // ---- layer 2 ----
  gather_bn<true><<<gatherGrid, 256, 0, stream>>>((const uint*)bufB, rowptr, cols, st1,
                                                  g1, be1, (uint*)bufA);
  gin_mlp<<<mlpGrid, 256, 0, stream>>>(bufA, pW2a, b2a, pW2b, b2b, bufB, st2);

  // ---- layer 3 ----
  gather_bn<true><<<gatherGrid, 256, 0, stream>>>((const uint*)bufB, rowptr, cols, st2,
                                                  g2, be2, (uint*)bufA);
  gin_mlp_out<<<mlpGrid, 256, 0, stream>>>(bufA, pW5a, b5a, W5b, b5b, o2buf, st3);
  bn_apply2<<<(Nn * 2 + 255) / 256, 256, 0, stream>>>(o2buf, st3, g5, be5,
                                                      (float*)d_out, Nn);
}